// Round 2
// baseline (64.751 us; speedup 1.0000x reference)
//
#include <hip/hip_runtime.h>

#define Bn 512

// sigmoid((sk - sj)/tau) = 1 / (1 + exp2(tj - tk)), t = s * log2(e)/tau
__device__ __forceinline__ float sigterm(float tj, float tk) {
    float e = __builtin_amdgcn_exp2f(tj - tk);
    return __builtin_amdgcn_rcpf(1.0f + e);
}

__global__ __launch_bounds__(1024, 8) void srap_main(
        const float* __restrict__ scores,
        const float* __restrict__ target,
        float* __restrict__ ap) {
    __shared__ __align__(16) float t[Bn];
    __shared__ float pA[Bn], pP[Bn];
    __shared__ float cs[16], ts[16];

    const int b   = blockIdx.x;
    const int tid = threadIdx.x;          // 0..1023
    const int j   = tid & (Bn - 1);       // output column
    const int h   = tid >> 9;             // k-half: 0 or 1

    const float C = 144.26950408889634f;  // log2(e) / tau, tau = 0.01
    if (tid < Bn) t[tid] = scores[(size_t)b * Bn + tid] * C;
    __syncthreads();

    const float tj = t[j];
    const float4* __restrict__ trow = (const float4*)(target + (size_t)j * Bn);

    float A = 0.0f;  // partial sum_k sigmoid
    float P = 0.0f;  // partial sum_k sigmoid * target[j,k]

    const int k4beg = h * (Bn / 8);       // 64 float4 chunks per half
#pragma unroll 4
    for (int k4 = k4beg; k4 < k4beg + Bn / 8; ++k4) {
        const float4 p  = trow[k4];
        const float4 tk = *(const float4*)(&t[k4 * 4]);  // uniform LDS broadcast

        float s0 = sigterm(tj, tk.x);
        float s1 = sigterm(tj, tk.y);
        float s2 = sigterm(tj, tk.z);
        float s3 = sigterm(tj, tk.w);

        A += (s0 + s1) + (s2 + s3);
        P = fmaf(s0, p.x, P);
        P = fmaf(s1, p.y, P);
        P = fmaf(s2, p.z, P);
        P = fmaf(s3, p.w, P);
    }

    if (h == 1) { pA[j] = A; pP[j] = P; }
    __syncthreads();

    float c = 0.0f, tt = 0.0f;
    if (h == 0) {
        // sim_all_rk = (A_full - 0.5 [diag sig]) + 1.0 [self] = A_full + 0.5
        const float A_all = A + pA[j] + 0.5f;
        const float tbj   = target[(size_t)b * Bn + j];
        // pos sum = P_full - 0.5 (diag: sig(0)*tgt[j,j] = 0.5); +target, *target
        const float Ppos  = P + pP[j] - 0.5f + tbj;
        c  = (Ppos * tbj) / A_all;
        tt = tbj;
    }

    // block reduction across 16 waves (upper 8 waves contribute zeros)
    for (int off = 32; off; off >>= 1) {
        c  += __shfl_down(c, off);
        tt += __shfl_down(tt, off);
    }
    const int wave = tid >> 6;
    const int lane = tid & 63;
    if (lane == 0) { cs[wave] = c; ts[wave] = tt; }
    __syncthreads();
    if (tid == 0) {
        float csum = 0.0f, tsum = 0.0f;
#pragma unroll
        for (int w = 0; w < 16; ++w) { csum += cs[w]; tsum += ts[w]; }
        ap[b] = csum / tsum;
    }
}

__global__ void srap_final(const float* __restrict__ ap, float* __restrict__ out) {
    const int lane = threadIdx.x;  // 64 threads
    float s = 0.0f;
#pragma unroll
    for (int i = 0; i < Bn / 64; ++i) s += ap[lane + i * 64];
    for (int off = 32; off; off >>= 1) s += __shfl_down(s, off);
    if (lane == 0) out[0] = 1.0f - s * (1.0f / Bn);
}

extern "C" void kernel_launch(void* const* d_in, const int* in_sizes, int n_in,
                              void* d_out, int out_size, void* d_ws, size_t ws_size,
                              hipStream_t stream) {
    const float* scores = (const float*)d_in[0];
    const float* target = (const float*)d_in[1];
    float* out = (float*)d_out;
    float* ap  = (float*)d_ws;   // 512 floats

    srap_main<<<dim3(Bn), dim3(1024), 0, stream>>>(scores, target, ap);
    srap_final<<<dim3(1), dim3(64), 0, stream>>>(ap, out);
}

// Round 3
// 47.499 us; speedup vs baseline: 1.3632x; 1.3632x over previous
//
#include <hip/hip_runtime.h>

#define Bn 512
#define KT 32   // k-tile columns staged in LDS per iteration

// sigmoid((sk - sj)/tau) = 1 / (1 + exp2(tj - tk)), t = s * log2(e)/tau
__device__ __forceinline__ float sigterm(float tj, float tk) {
    float e = __builtin_amdgcn_exp2f(tj - tk);
    return __builtin_amdgcn_rcpf(1.0f + e);
}

__global__ __launch_bounds__(1024, 8) void srap_main(
        const float* __restrict__ scores,
        const float* __restrict__ target,
        float* __restrict__ ap) {
    __shared__ __align__(16) float t[Bn];
    __shared__ __align__(16) float tile[Bn * KT];   // 64 KB, XOR-swizzled granules
    __shared__ float pA[Bn], pP[Bn];
    __shared__ float cs[16], ts[16];

    const int b   = blockIdx.x;
    const int tid = threadIdx.x;          // 0..1023
    const int j   = tid & (Bn - 1);       // output column
    const int h   = tid >> 9;             // k-half within tile: 0 or 1

    const float C = 144.26950408889634f;  // log2(e) / tau, tau = 0.01
    if (tid < Bn) t[tid] = scores[(size_t)b * Bn + tid] * C;

    // staging mapping: 8 threads per row, 8 float4 granules per 32-float row
    const int srow = tid >> 3;            // 0..127 (+p*128)
    const int sg   = tid & 7;             // source granule index
    const float4* __restrict__ gt = (const float4*)target;

    __syncthreads();
    const float tj = t[j];
    const int jx = j & 7;                 // XOR key for this thread's row

    float A = 0.0f;  // sum_k sigmoid
    float P = 0.0f;  // sum_k sigmoid * target[j,k]

    for (int kt = 0; kt < Bn / KT; ++kt) {
        const int kc4 = kt * (KT / 4);    // float4 column base in target
        // ---- stage tgt[0:512, kt*32 .. +32) -> LDS, coalesced + swizzled ----
        #pragma unroll
        for (int p = 0; p < 4; ++p) {
            const int r = srow + p * 128;
            const float4 v = gt[r * (Bn / 4) + kc4 + sg];
            const int gsw = sg ^ (r & 7); // granule XOR swizzle
            *(float4*)(&tile[r * KT + gsw * 4]) = v;
        }
        __syncthreads();

        // ---- consume: this thread's row j, k-half h (16 elems = 4 float4) ----
        #pragma unroll
        for (int qq = 0; qq < 4; ++qq) {
            const int g = h * 4 + qq;     // logical granule in row
            const float4 pv = *(const float4*)(&tile[j * KT + ((g ^ jx) * 4)]);
            const float4 tk = *(const float4*)(&t[kt * KT + g * 4]);  // broadcast

            float s0 = sigterm(tj, tk.x);
            float s1 = sigterm(tj, tk.y);
            float s2 = sigterm(tj, tk.z);
            float s3 = sigterm(tj, tk.w);

            A += (s0 + s1) + (s2 + s3);
            P = fmaf(s0, pv.x, P);
            P = fmaf(s1, pv.y, P);
            P = fmaf(s2, pv.z, P);
            P = fmaf(s3, pv.w, P);
        }
        __syncthreads();                  // tile reused next iteration
    }

    if (h == 1) { pA[j] = A; pP[j] = P; }
    __syncthreads();

    float c = 0.0f, tt = 0.0f;
    if (h == 0) {
        // sim_all_rk = (A_full - 0.5 [diag sig]) + 1.0 [self] = A_full + 0.5
        const float A_all = A + pA[j] + 0.5f;
        const float tbj   = target[(size_t)b * Bn + j];
        // pos sum = P_full - 0.5 (diag); +target, *target
        const float Ppos  = P + pP[j] - 0.5f + tbj;
        c  = (Ppos * tbj) / A_all;
        tt = tbj;
    }

    // block reduction across 16 waves (upper 8 waves contribute zeros)
    for (int off = 32; off; off >>= 1) {
        c  += __shfl_down(c, off);
        tt += __shfl_down(tt, off);
    }
    const int wave = tid >> 6;
    const int lane = tid & 63;
    if (lane == 0) { cs[wave] = c; ts[wave] = tt; }
    __syncthreads();
    if (tid == 0) {
        float csum = 0.0f, tsum = 0.0f;
        #pragma unroll
        for (int w = 0; w < 16; ++w) { csum += cs[w]; tsum += ts[w]; }
        ap[b] = csum / tsum;
    }
}

__global__ void srap_final(const float* __restrict__ ap, float* __restrict__ out) {
    const int lane = threadIdx.x;  // 64 threads
    float s = 0.0f;
#pragma unroll
    for (int i = 0; i < Bn / 64; ++i) s += ap[lane + i * 64];
    for (int off = 32; off; off >>= 1) s += __shfl_down(s, off);
    if (lane == 0) out[0] = 1.0f - s * (1.0f / Bn);
}

extern "C" void kernel_launch(void* const* d_in, const int* in_sizes, int n_in,
                              void* d_out, int out_size, void* d_ws, size_t ws_size,
                              hipStream_t stream) {
    const float* scores = (const float*)d_in[0];
    const float* target = (const float*)d_in[1];
    float* out = (float*)d_out;
    float* ap  = (float*)d_ws;   // 512 floats

    srap_main<<<dim3(Bn), dim3(1024), 0, stream>>>(scores, target, ap);
    srap_final<<<dim3(1), dim3(64), 0, stream>>>(ap, out);
}

// Round 4
// 39.310 us; speedup vs baseline: 1.6472x; 1.2083x over previous
//
#include <hip/hip_runtime.h>

#define Bn 512
#define BC 32   // b rows per block
#define JT 32   // j columns per block

// sigmoid((sk - sj)/tau) = 1 / (1 + exp2(tj - tk)), t = s * log2(e)/tau
__device__ __forceinline__ float sigterm(float tj, float tk) {
    float e = __builtin_amdgcn_exp2f(tj - tk);
    return __builtin_amdgcn_rcpf(1.0f + e);
}

__global__ __launch_bounds__(1024, 4) void srap_main(
        const float* __restrict__ scores,
        const float* __restrict__ target,
        float* __restrict__ wsC,
        float* __restrict__ wsT) {
    // scores chunk transposed+packed+swizzled:
    // granule g(k4,b) = k4*32 + (b ^ (k4&31)) holds scores[b0+b][4k4..4k4+3]*C
    __shared__ __align__(16) float sT[(Bn / 4) * BC * 4];   // 64 KB
    __shared__ float partC[16 * BC], partT[16 * BC];

    const int tid = threadIdx.x;
    const int b0 = blockIdx.x * BC;
    const int j0 = blockIdx.y * JT;
    const int jl = tid >> 5;      // local j (0..31)
    const int bl = tid & 31;      // local b (0..31)

    const float C = 144.26950408889634f;  // log2(e)/tau, tau = 0.01

    // ---- stage scores[b0..b0+31][0..511]*C -> sT (transposed, swizzled) ----
    {
        // here jl plays the role of the staged b-row, bl the low k4 bits
        const float4* g4 = (const float4*)(scores + (size_t)(b0 + jl) * Bn);
        #pragma unroll
        for (int i = 0; i < 4; ++i) {
            const int k4 = bl + i * 32;
            float4 v = g4[k4];
            v.x *= C; v.y *= C; v.z *= C; v.w *= C;
            const int g = k4 * BC + (jl ^ (k4 & 31));
            *(float4*)(&sT[g * 4]) = v;
        }
    }
    __syncthreads();

    const int j = j0 + jl;
    const float tj = scores[(size_t)(b0 + bl) * Bn + j] * C;  // same mul as staged
    const float4* __restrict__ trow = (const float4*)(target + (size_t)j * Bn);

    float A = 0.0f;  // sum_k sigmoid
    float P = 0.0f;  // sum_k sigmoid * target[j,k]

    #pragma unroll 4
    for (int k4 = 0; k4 < Bn / 4; ++k4) {
        const float4 w = trow[k4];            // 2 distinct addrs/wave, L1/L2 hit
        const int g = k4 * BC + (bl ^ (k4 & 31));
        const float4 tk = *(const float4*)(&sT[g * 4]);

        float s0 = sigterm(tj, tk.x);
        float s1 = sigterm(tj, tk.y);
        float s2 = sigterm(tj, tk.z);
        float s3 = sigterm(tj, tk.w);
        A += (s0 + s1) + (s2 + s3);
        P = fmaf(s0, w.x, P);
        P = fmaf(s1, w.y, P);
        P = fmaf(s2, w.z, P);
        P = fmaf(s3, w.w, P);
    }

    // diag k=j contributes exactly 0.5 to both A and P (tgt[j,j]=1):
    // sim_all = A + 0.5;  pos = P - 0.5 + target[b,j]
    const float tbj = target[(size_t)(b0 + bl) * Bn + j];
    const float c = (P - 0.5f + tbj) * tbj / (A + 0.5f);

    // combine the 2 j's held by this wave (lane+32 = same b, j+1)
    float c2 = c + __shfl_down(c, 32);
    float t2 = tbj + __shfl_down(tbj, 32);
    const int wave = tid >> 6;
    if ((tid & 63) < 32) { partC[wave * 32 + bl] = c2; partT[wave * 32 + bl] = t2; }
    __syncthreads();

    if (tid < BC) {
        float cs = 0.0f, ts = 0.0f;
        #pragma unroll
        for (int w = 0; w < 16; ++w) { cs += partC[w * 32 + tid]; ts += partT[w * 32 + tid]; }
        wsC[(size_t)blockIdx.y * Bn + b0 + tid] = cs;
        wsT[(size_t)blockIdx.y * Bn + b0 + tid] = ts;
    }
}

__global__ __launch_bounds__(512) void srap_final(
        const float* __restrict__ wsC, const float* __restrict__ wsT,
        float* __restrict__ out) {
    __shared__ float red[8];
    const int b = threadIdx.x;  // 512 threads, one per batch row
    float num = 0.0f, den = 0.0f;
    #pragma unroll
    for (int jt = 0; jt < Bn / JT; ++jt) {
        num += wsC[jt * Bn + b];
        den += wsT[jt * Bn + b];
    }
    float apb = num / den;
    for (int off = 32; off; off >>= 1) apb += __shfl_down(apb, off);
    if ((b & 63) == 0) red[b >> 6] = apb;
    __syncthreads();
    if (b == 0) {
        float s = 0.0f;
        #pragma unroll
        for (int w = 0; w < 8; ++w) s += red[w];
        out[0] = 1.0f - s * (1.0f / Bn);
    }
}

extern "C" void kernel_launch(void* const* d_in, const int* in_sizes, int n_in,
                              void* d_out, int out_size, void* d_ws, size_t ws_size,
                              hipStream_t stream) {
    const float* scores = (const float*)d_in[0];
    const float* target = (const float*)d_in[1];
    float* out = (float*)d_out;
    float* wsC = (float*)d_ws;                       // 16*512 floats
    float* wsT = wsC + (Bn / JT) * Bn;               // 16*512 floats

    srap_main<<<dim3(Bn / BC, Bn / JT), dim3(1024), 0, stream>>>(scores, target, wsC, wsT);
    srap_final<<<dim3(1), dim3(512), 0, stream>>>(wsC, wsT, out);
}